// Round 1
// baseline (371.533 us; speedup 1.0000x reference)
//
#include <hip/hip_runtime.h>

// DeformConv2D: b=4, c=128, H=W=64, outc=128, KS=3, PAD=1, N=9
// out[b,o,i,j] = sum_{c,k} weight[o,c,k] * bilinear(x_pad[b,c], p(b,k,i,j))

#define BB   4
#define CIN  128
#define HH   64
#define WW   64
#define OC   128
#define NPT  9
#define CCH  16   // channel chunk

// ws layout: Wt[(c*9+k)*128 + o] = weight[o*1152 + c*9 + k]
__global__ __launch_bounds__(256) void transpose_w_kernel(const float* __restrict__ w,
                                                          float* __restrict__ wt) {
    int t = blockIdx.x * 256 + threadIdx.x;
    if (t < OC * CIN * NPT) {
        int o = t / (CIN * NPT);
        int ck = t % (CIN * NPT);
        wt[ck * OC + o] = w[t];
    }
}

__global__ __launch_bounds__(256) void deform_main_kernel(
    const float* __restrict__ x, const float* __restrict__ off,
    const float* __restrict__ w, const float* __restrict__ wt,
    float* __restrict__ out, int use_wt)
{
    // sample descriptors for 9 taps x 32 pixels
    __shared__ int   sIdx[NPT][32][4];
    __shared__ float sG[NPT][32][4];
    __shared__ float sA[CCH][NPT][32];   // x_off chunk: [cc][k][p]

    const int bidx = blockIdx.x;          // 512 blocks: b(4) * i(64) * jt(2)
    const int b   = bidx >> 7;
    const int i   = (bidx >> 1) & 63;
    const int j0  = (bidx & 1) * 32;
    const int tid = threadIdx.x;

    // ---- Phase S: sampling geometry (matches reference exactly) ----
    for (int m = tid; m < NPT * 32; m += 256) {
        int k = m >> 5, p = m & 31;
        int j = j0 + p;
        // offset reorder: x-offset = orig channel 2k, y-offset = orig channel 2k+1
        float ox = off[(((b * 18) + 2 * k) * 64 + i) * 64 + j];
        float oy = off[(((b * 18) + 2 * k + 1) * 64 + i) * 64 + j];
        // p = p0 + p_n + offset ; p0x = i+1, pnx = k/3-1 ; p0y = j+1, pny = k%3-1
        float px = (float)(i + k / 3) + ox;
        float py = (float)(j + k % 3) + oy;
        float fx = floorf(px), fy = floorf(py);
        int qltx = (int)fminf(fmaxf(fx, 0.f), 65.f);
        int qlty = (int)fminf(fmaxf(fy, 0.f), 65.f);
        int qrbx = (int)fminf(fmaxf(fx + 1.f, 0.f), 65.f);
        int qrby = (int)fminf(fmaxf(fy + 1.f, 0.f), 65.f);
        // pad-snap mask (reference: mask over ORIGINAL px/py, then snap to floor)
        if (px < 1.f || px > 64.f) px = fx;
        if (py < 1.f || py > 64.f) py = fy;
        px = fminf(fmaxf(px, 0.f), 65.f);
        py = fminf(fmaxf(py, 0.f), 65.f);
        float wxl = 1.f + (float)qltx - px;
        float wxr = 1.f - ((float)qrbx - px);
        float wyl = 1.f + (float)qlty - py;
        float wyr = 1.f - ((float)qrby - py);
        float g[4] = { wxl * wyl, wxr * wyr, wxl * wyr, wxr * wyl };
        int qx[4] = { qltx, qrbx, qltx, qrbx };
        int qy[4] = { qlty, qrby, qrby, qrby };
        // corners: lt=(qltx,qlty) rb=(qrbx,qrby) lb=(qltx,qrby) rt=(qrbx,qlty)
        qy[3] = qlty;
        #pragma unroll
        for (int cr = 0; cr < 4; ++cr) {
            bool inb = (qx[cr] >= 1) && (qx[cr] <= 64) && (qy[cr] >= 1) && (qy[cr] <= 64);
            sIdx[k][p][cr] = inb ? ((qx[cr] - 1) * WW + (qy[cr] - 1)) : 0;
            sG[k][p][cr]   = inb ? g[cr] : 0.f;
        }
    }
    __syncthreads();

    const int og = tid >> 3, pg = tid & 7;
    const int o0 = og * 4, p0 = pg * 4;
    float acc[4][4] = {};

    const float* sAf = &sA[0][0][0];

    for (int c0 = 0; c0 < CIN; c0 += CCH) {
        // ---- stage x_off chunk into LDS ----
        #pragma unroll
        for (int it = 0; it < (CCH * NPT * 32) / 256; ++it) {
            int m = tid + it * 256;
            int cc = m / (NPT * 32);
            int r  = m % (NPT * 32);
            int k = r >> 5, p = r & 31;
            const float* xb = x + (size_t)((b * CIN + c0 + cc) << 12);
            int4   id = *(const int4*)&sIdx[k][p][0];
            float4 g  = *(const float4*)&sG[k][p][0];
            sA[cc][k][p] = g.x * xb[id.x] + g.y * xb[id.y] + g.z * xb[id.z] + g.w * xb[id.w];
        }
        __syncthreads();

        // ---- inner contraction ----
        if (use_wt) {
            const float* wtp = wt + (size_t)(c0 * NPT) * OC + o0;
            #pragma unroll 4
            for (int ck = 0; ck < CCH * NPT; ++ck) {
                float4 a  = *(const float4*)(sAf + ck * 32 + p0);
                float4 wv = *(const float4*)(wtp + ck * OC);
                float av[4] = { a.x, a.y, a.z, a.w };
                float wvv[4] = { wv.x, wv.y, wv.z, wv.w };
                #pragma unroll
                for (int oo = 0; oo < 4; ++oo)
                    #pragma unroll
                    for (int pp = 0; pp < 4; ++pp)
                        acc[oo][pp] += wvv[oo] * av[pp];
            }
        } else {
            for (int cc = 0; cc < CCH; ++cc) {
                #pragma unroll
                for (int k = 0; k < NPT; ++k) {
                    float4 a = *(const float4*)(sAf + (cc * NPT + k) * 32 + p0);
                    float av[4] = { a.x, a.y, a.z, a.w };
                    #pragma unroll
                    for (int oo = 0; oo < 4; ++oo) {
                        float wv = w[(size_t)(o0 + oo) * (CIN * NPT) + (c0 + cc) * NPT + k];
                        #pragma unroll
                        for (int pp = 0; pp < 4; ++pp)
                            acc[oo][pp] += wv * av[pp];
                    }
                }
            }
        }
        __syncthreads();
    }

    // ---- epilogue ----
    float* op = out + (size_t)((b * OC + o0) * HH + i) * WW + j0 + p0;
    #pragma unroll
    for (int oo = 0; oo < 4; ++oo) {
        float4 v = make_float4(acc[oo][0], acc[oo][1], acc[oo][2], acc[oo][3]);
        *(float4*)(op + (size_t)oo * HH * WW) = v;
    }
}

extern "C" void kernel_launch(void* const* d_in, const int* in_sizes, int n_in,
                              void* d_out, int out_size, void* d_ws, size_t ws_size,
                              hipStream_t stream) {
    const float* x   = (const float*)d_in[0];
    const float* off = (const float*)d_in[1];
    const float* w   = (const float*)d_in[2];
    float* out = (float*)d_out;

    const size_t wt_bytes = (size_t)CIN * NPT * OC * sizeof(float);
    int use_wt = (ws_size >= wt_bytes) ? 1 : 0;
    float* wt = (float*)d_ws;

    if (use_wt) {
        transpose_w_kernel<<<(OC * CIN * NPT + 255) / 256, 256, 0, stream>>>(w, wt);
    }
    deform_main_kernel<<<BB * HH * 2, 256, 0, stream>>>(x, off, w, wt, out, use_wt);
}

// Round 2
// 150.671 us; speedup vs baseline: 2.4659x; 2.4659x over previous
//
#include <hip/hip_runtime.h>

// DeformConv2D: b=4, c=128, H=W=64, outc=128, KS=3, PAD=1, N=9
// out[b,o,i,j] = sum_{ck} W[o][ck] * A[ck][(b,i,j)],  ck = c*9+tap, K=1152
// Contraction via mfma_f32_16x16x32_bf16; bilinear sampling staged to LDS.

typedef __bf16 v8bf16 __attribute__((ext_vector_type(8)));
typedef float  f32x4  __attribute__((ext_vector_type(4)));

#define CIN  128
#define NPT  9
#define KTOT 1152    // CIN*NPT
#define OC   128
#define PX   16      // pixels per block (one row segment)
#define KC   64      // k-chunk per barrier period
#define LDB  (KC + 8) // Bt row stride in bf16 (144 B: 16B-aligned, 2-way banks)

__global__ __launch_bounds__(256) void wconv_kernel(const float* __restrict__ w,
                                                    __bf16* __restrict__ wbf) {
    int t = blockIdx.x * 256 + threadIdx.x;
    if (t < OC * KTOT) wbf[t] = (__bf16)w[t];
}

__global__ __launch_bounds__(256, 4) void deform_mfma_kernel(
    const float* __restrict__ x, const float* __restrict__ off,
    const float* __restrict__ w, const __bf16* __restrict__ wbf,
    float* __restrict__ out, int use_wt)
{
    __shared__ __align__(16) int    sIdx[NPT][PX][4];
    __shared__ __align__(16) float  sG[NPT][PX][4];
    __shared__ __align__(16) __bf16 Bt[PX][LDB];

    const int bidx = blockIdx.x;           // 1024 = b(4) * i(64) * jq(4)
    const int b   = bidx >> 8;
    const int i   = (bidx >> 2) & 63;
    const int j0  = (bidx & 3) * PX;
    const int tid = threadIdx.x;

    // ---- Phase S: sampling geometry (identical math to verified round-1) ----
    if (tid < NPT * PX) {
        int k = tid >> 4, p = tid & 15;
        int j = j0 + p;
        float ox = off[(((b * 18) + 2 * k) * 64 + i) * 64 + j];
        float oy = off[(((b * 18) + 2 * k + 1) * 64 + i) * 64 + j];
        float px = (float)(i + k / 3) + ox;
        float py = (float)(j + k % 3) + oy;
        float fx = floorf(px), fy = floorf(py);
        int qltx = (int)fminf(fmaxf(fx, 0.f), 65.f);
        int qlty = (int)fminf(fmaxf(fy, 0.f), 65.f);
        int qrbx = (int)fminf(fmaxf(fx + 1.f, 0.f), 65.f);
        int qrby = (int)fminf(fmaxf(fy + 1.f, 0.f), 65.f);
        if (px < 1.f || px > 64.f) px = fx;
        if (py < 1.f || py > 64.f) py = fy;
        px = fminf(fmaxf(px, 0.f), 65.f);
        py = fminf(fmaxf(py, 0.f), 65.f);
        float wxl = 1.f + (float)qltx - px;
        float wxr = 1.f - ((float)qrbx - px);
        float wyl = 1.f + (float)qlty - py;
        float wyr = 1.f - ((float)qrby - py);
        float g[4] = { wxl * wyl, wxr * wyr, wxl * wyr, wxr * wyl };
        int qx[4] = { qltx, qrbx, qltx, qrbx };
        int qy[4] = { qlty, qrby, qrby, qlty };
        #pragma unroll
        for (int cr = 0; cr < 4; ++cr) {
            bool inb = (qx[cr] >= 1) && (qx[cr] <= 64) && (qy[cr] >= 1) && (qy[cr] <= 64);
            sIdx[k][p][cr] = inb ? ((qx[cr] - 1) * 64 + (qy[cr] - 1)) : 0;
            sG[k][p][cr]   = inb ? g[cr] : 0.f;
        }
    }
    __syncthreads();

    const int l    = tid & 63;
    const int wv   = tid >> 6;   // wave 0..3 -> o base wv*32
    const int quad = l >> 4;
    const int lr   = l & 15;

    f32x4 acc0 = {0.f, 0.f, 0.f, 0.f};
    f32x4 acc1 = {0.f, 0.f, 0.f, 0.f};

    const float* xb_base = x + ((size_t)b << 19);  // b*128*4096

    for (int kc0 = 0; kc0 < KTOT; kc0 += KC) {
        // ---- stage B-tile: 64 k x 16 px bilinear samples -> Bt[px][kk] ----
        #pragma unroll
        for (int it = 0; it < 4; ++it) {
            int m  = tid + it * 256;
            int kk = m >> 4, p = m & 15;
            int ck = kc0 + kk;
            int c  = ck / 9;
            int tap = ck - c * 9;
            const float* xb = xb_base + ((size_t)c << 12);
            int4   id = *(const int4*)&sIdx[tap][p][0];
            float4 g  = *(const float4*)&sG[tap][p][0];
            float v = g.x * xb[id.x] + g.y * xb[id.y] + g.z * xb[id.z] + g.w * xb[id.w];
            Bt[p][kk] = (__bf16)v;
        }
        __syncthreads();

        // ---- MFMA: o(32 per wave) x px(16), K=64 in two k-halves ----
        #pragma unroll
        for (int kh = 0; kh < 2; ++kh) {
            v8bf16 bfrag = *(const v8bf16*)&Bt[lr][kh * 32 + quad * 8];
            #pragma unroll
            for (int mt = 0; mt < 2; ++mt) {
                int o = wv * 32 + mt * 16 + lr;
                v8bf16 afrag;
                if (use_wt) {
                    afrag = *(const v8bf16*)(wbf + (size_t)o * KTOT + kc0 + kh * 32 + quad * 8);
                } else {
                    const float* wp = w + (size_t)o * KTOT + kc0 + kh * 32 + quad * 8;
                    #pragma unroll
                    for (int e = 0; e < 8; ++e) afrag[e] = (__bf16)wp[e];
                }
                if (mt == 0)
                    acc0 = __builtin_amdgcn_mfma_f32_16x16x32_bf16(afrag, bfrag, acc0, 0, 0, 0);
                else
                    acc1 = __builtin_amdgcn_mfma_f32_16x16x32_bf16(afrag, bfrag, acc1, 0, 0, 0);
            }
        }
        __syncthreads();
    }

    // ---- epilogue: D row = o(quad*4+r), col = px(lr) ----
    #pragma unroll
    for (int mt = 0; mt < 2; ++mt) {
        int obase = wv * 32 + mt * 16 + quad * 4;
        float* op = out + (((size_t)(b * OC + obase)) << 12) + (i << 6) + j0 + lr;
        f32x4 a = (mt == 0) ? acc0 : acc1;
        #pragma unroll
        for (int r = 0; r < 4; ++r)
            op[(size_t)r << 12] = a[r];
    }
}

extern "C" void kernel_launch(void* const* d_in, const int* in_sizes, int n_in,
                              void* d_out, int out_size, void* d_ws, size_t ws_size,
                              hipStream_t stream) {
    const float* x   = (const float*)d_in[0];
    const float* off = (const float*)d_in[1];
    const float* w   = (const float*)d_in[2];
    float* out = (float*)d_out;

    const size_t wbf_bytes = (size_t)OC * KTOT * sizeof(__bf16);
    int use_wt = (ws_size >= wbf_bytes) ? 1 : 0;
    __bf16* wbf = (__bf16*)d_ws;

    if (use_wt) {
        wconv_kernel<<<(OC * KTOT + 255) / 256, 256, 0, stream>>>(w, wbf);
    }
    deform_mfma_kernel<<<4 * 64 * 4, 256, 0, stream>>>(x, off, w, wbf, out, use_wt);
}

// Round 3
// 101.980 us; speedup vs baseline: 3.6432x; 1.4775x over previous
//
#include <hip/hip_runtime.h>

// DeformConv2D b=4,c=128,H=W=64,outc=128,KS=3,PAD=1,N=9
// out[(b,i,j),o] = sum_ck W[o][ck] * A[ck][(b,i,j)], ck = tap*128 + c, K=1152
// Stage 1: x NCHW fp32 -> x_t (b,hw,c) bf16 (channels-last, coalesced sampling)
// Stage 2: weight -> MFMA A-fragment layout wfrag[ot][ks][lane][8] bf16
// Stage 3: per (b,i,j0..j0+31): full B-tile bilinear -> LDS, then 36 K-step MFMA

typedef __bf16  v8bf16 __attribute__((ext_vector_type(8)));
typedef __bf16  bf16x2 __attribute__((ext_vector_type(2)));
typedef float   f32x4  __attribute__((ext_vector_type(4)));
typedef unsigned short ushort4v __attribute__((ext_vector_type(4)));
typedef _Float16 half4v __attribute__((ext_vector_type(4)));

#define CIN  128
#define NPT  9
#define KTOT 1152
#define OC   128
#define PX   32
#define NDESC (NPT * PX)      // 288
#define KSTEPS 36             // KTOT/32
#define LDB  (KTOT + 8)       // 1160 bf16 = 2320 B row stride (16B aligned, 2-way banks)

// ---------- x NCHW fp32 -> channels-last bf16 ----------
__global__ __launch_bounds__(256) void xpose_kernel(const float* __restrict__ x,
                                                    __bf16* __restrict__ xt) {
    __shared__ float tile[64][33];
    const int bidx = blockIdx.x;            // 4 b * 64 hwt * 4 ct
    const int b   = bidx >> 8;
    const int hw0 = ((bidx >> 2) & 63) * 64;
    const int c0  = (bidx & 3) * 32;
    const int tid = threadIdx.x;
    #pragma unroll
    for (int r = 0; r < 8; ++r) {
        int c_l  = (tid >> 6) + r * 4;
        int hw_l = tid & 63;
        tile[hw_l][c_l] = x[((size_t)(b * CIN + c0 + c_l) << 12) + hw0 + hw_l];
    }
    __syncthreads();
    #pragma unroll
    for (int r = 0; r < 8; ++r) {
        int hw_l = (tid >> 5) + r * 8;
        int c_l  = tid & 31;
        xt[((size_t)(b * 4096 + hw0 + hw_l)) * CIN + c0 + c_l] = (__bf16)tile[hw_l][c_l];
    }
}

// ---------- weight -> A-fragment layout ----------
// wfrag[((ot*36+ks)*64 + lane)*8 + e] = (bf16) w[o*1152 + c*9 + tap]
//   o = ot*16 + (lane&15), k = ks*32 + (lane>>4)*8 + e, tap = k>>7, c = k&127
__global__ __launch_bounds__(256) void wfrag_kernel(const float* __restrict__ w,
                                                    __bf16* __restrict__ wfrag) {
    int t = blockIdx.x * 256 + threadIdx.x;     // [0, 8*36*64)
    if (t >= 8 * KSTEPS * 64) return;
    int lane = t & 63;
    int ks   = (t >> 6) % KSTEPS;
    int ot   = t / (KSTEPS * 64);
    int o    = ot * 16 + (lane & 15);
    v8bf16 frag;
    #pragma unroll
    for (int e = 0; e < 8; ++e) {
        int k   = ks * 32 + (lane >> 4) * 8 + e;
        int tap = k >> 7, c = k & 127;
        frag[e] = (__bf16)w[(size_t)o * KTOT + c * NPT + tap];
    }
    *(v8bf16*)(wfrag + (size_t)t * 8) = frag;
}

__global__ __launch_bounds__(512, 4) void deform_mfma_kernel(
    const float* __restrict__ x, const float* __restrict__ off,
    const float* __restrict__ w, const __bf16* __restrict__ wfrag,
    const __bf16* __restrict__ xt, float* __restrict__ out, int mode)
{
    __shared__ __align__(16) __bf16 Bt[PX][LDB];          // 74240 B
    __shared__ __align__(8)  unsigned short sIdxP[NDESC][4];
    __shared__ __align__(8)  _Float16      sGP[NDESC][4];

    const int bidx = blockIdx.x;          // 512 = b(4) * i(64) * jh(2)
    const int b   = bidx >> 7;
    const int i   = (bidx >> 1) & 63;
    const int j0  = (bidx & 1) * PX;
    const int tid = threadIdx.x;

    // ---- Phase S: sampling geometry (d = tap*32 + p) ----
    if (tid < NDESC) {
        int k = tid >> 5, p = tid & 31;
        int j = j0 + p;
        float ox = off[(((b * 18) + 2 * k) * 64 + i) * 64 + j];
        float oy = off[(((b * 18) + 2 * k + 1) * 64 + i) * 64 + j];
        float px = (float)(i + k / 3) + ox;
        float py = (float)(j + k % 3) + oy;
        float fx = floorf(px), fy = floorf(py);
        int qltx = (int)fminf(fmaxf(fx, 0.f), 65.f);
        int qlty = (int)fminf(fmaxf(fy, 0.f), 65.f);
        int qrbx = (int)fminf(fmaxf(fx + 1.f, 0.f), 65.f);
        int qrby = (int)fminf(fmaxf(fy + 1.f, 0.f), 65.f);
        if (px < 1.f || px > 64.f) px = fx;
        if (py < 1.f || py > 64.f) py = fy;
        px = fminf(fmaxf(px, 0.f), 65.f);
        py = fminf(fmaxf(py, 0.f), 65.f);
        float wxl = 1.f + (float)qltx - px;
        float wxr = 1.f - ((float)qrbx - px);
        float wyl = 1.f + (float)qlty - py;
        float wyr = 1.f - ((float)qrby - py);
        float g[4] = { wxl * wyl, wxr * wyr, wxl * wyr, wxr * wyl };
        int qx[4] = { qltx, qrbx, qltx, qrbx };
        int qy[4] = { qlty, qrby, qrby, qlty };
        #pragma unroll
        for (int cr = 0; cr < 4; ++cr) {
            bool inb = (qx[cr] >= 1) && (qx[cr] <= 64) && (qy[cr] >= 1) && (qy[cr] <= 64);
            sIdxP[tid][cr] = inb ? (unsigned short)((qx[cr] - 1) * 64 + (qy[cr] - 1)) : 0;
            sGP[tid][cr]   = inb ? (_Float16)g[cr] : (_Float16)0.f;
        }
    }
    __syncthreads();

    const int l  = tid & 63;
    const int wv = tid >> 6;   // 0..7

    // ---- Stage full B-tile: wave wv handles descriptors [wv*36, wv*36+36) ----
    if (mode == 2) {
        const __bf16* xtb = xt + ((size_t)b * 4096) * CIN;
        #pragma unroll 2
        for (int dd = 0; dd < NDESC / 8; ++dd) {
            int d = wv * (NDESC / 8) + dd;
            int tap = d >> 5, p = d & 31;
            ushort4v id = *(const ushort4v*)&sIdxP[d][0];
            half4v   gh = *(const half4v*)&sGP[d][0];
            float s0 = 0.f, s1 = 0.f;
            #pragma unroll
            for (int cr = 0; cr < 4; ++cr) {
                unsigned int v = *(const unsigned int*)(xtb + (size_t)id[cr] * CIN + 2 * l);
                float c0, c1;
                unsigned int lo = v << 16, hi = v & 0xffff0000u;
                __builtin_memcpy(&c0, &lo, 4);
                __builtin_memcpy(&c1, &hi, 4);
                float gf = (float)gh[cr];
                s0 += gf * c0;
                s1 += gf * c1;
            }
            bf16x2 pr = { (__bf16)s0, (__bf16)s1 };
            *(bf16x2*)&Bt[p][tap * CIN + 2 * l] = pr;
        }
    } else {
        const float* xb = x + ((size_t)b * CIN << 12);
        for (int dd = 0; dd < NDESC / 8; ++dd) {
            int d = wv * (NDESC / 8) + dd;
            int tap = d >> 5, p = d & 31;
            ushort4v id = *(const ushort4v*)&sIdxP[d][0];
            half4v   gh = *(const half4v*)&sGP[d][0];
            float s0 = 0.f, s1 = 0.f;
            #pragma unroll
            for (int cr = 0; cr < 4; ++cr) {
                float gf = (float)gh[cr];
                s0 += gf * xb[((size_t)(2 * l) << 12) + id[cr]];
                s1 += gf * xb[((size_t)(2 * l + 1) << 12) + id[cr]];
            }
            bf16x2 pr = { (__bf16)s0, (__bf16)s1 };
            *(bf16x2*)&Bt[p][tap * CIN + 2 * l] = pr;
        }
    }
    __syncthreads();

    // ---- MFMA: wave wv -> px half (wv>>2), o pair base (wv&3)*32 ----
    const int ph   = wv >> 2;
    const int ob   = wv & 3;
    const int quad = l >> 4;
    const int lr   = l & 15;

    f32x4 acc0 = {0.f, 0.f, 0.f, 0.f};
    f32x4 acc1 = {0.f, 0.f, 0.f, 0.f};

    const __bf16* brow = &Bt[ph * 16 + lr][quad * 8];

    #pragma unroll 4
    for (int ks = 0; ks < KSTEPS; ++ks) {
        v8bf16 bfrag = *(const v8bf16*)(brow + ks * 32);
        #pragma unroll
        for (int mt = 0; mt < 2; ++mt) {
            int ot = ob * 2 + mt;
            v8bf16 afrag;
            if (mode >= 1) {
                afrag = *(const v8bf16*)(wfrag + (((size_t)ot * KSTEPS + ks) * 64 + l) * 8);
            } else {
                int o = ot * 16 + lr;
                #pragma unroll
                for (int e = 0; e < 8; ++e) {
                    int k = ks * 32 + quad * 8 + e;
                    int tap = k >> 7, c = k & 127;
                    afrag[e] = (__bf16)w[(size_t)o * KTOT + c * NPT + tap];
                }
            }
            if (mt == 0)
                acc0 = __builtin_amdgcn_mfma_f32_16x16x32_bf16(afrag, bfrag, acc0, 0, 0, 0);
            else
                acc1 = __builtin_amdgcn_mfma_f32_16x16x32_bf16(afrag, bfrag, acc1, 0, 0, 0);
        }
    }

    // ---- epilogue: row = o (quad*4+r), col = px (lr) ----
    #pragma unroll
    for (int mt = 0; mt < 2; ++mt) {
        int obase = ob * 32 + mt * 16 + quad * 4;
        float* op = out + (((size_t)(b * OC + obase)) << 12) + (i << 6) + j0 + ph * 16 + lr;
        f32x4 a = (mt == 0) ? acc0 : acc1;
        #pragma unroll
        for (int r = 0; r < 4; ++r)
            op[(size_t)r << 12] = a[r];
    }
}

extern "C" void kernel_launch(void* const* d_in, const int* in_sizes, int n_in,
                              void* d_out, int out_size, void* d_ws, size_t ws_size,
                              hipStream_t stream) {
    const float* x   = (const float*)d_in[0];
    const float* off = (const float*)d_in[1];
    const float* w   = (const float*)d_in[2];
    float* out = (float*)d_out;

    const size_t wfrag_bytes = (size_t)OC * KTOT * sizeof(__bf16);     // 294912
    const size_t xt_bytes    = (size_t)4 * 4096 * CIN * sizeof(__bf16); // 4 MB
    int mode = 0;
    if (ws_size >= wfrag_bytes + xt_bytes) mode = 2;
    else if (ws_size >= wfrag_bytes) mode = 1;

    __bf16* wfrag = (__bf16*)d_ws;
    __bf16* xt    = (__bf16*)((char*)d_ws + wfrag_bytes);

    if (mode >= 1) {
        wfrag_kernel<<<(8 * KSTEPS * 64 + 255) / 256, 256, 0, stream>>>(w, wfrag);
    }
    if (mode == 2) {
        xpose_kernel<<<4 * 64 * 4, 256, 0, stream>>>(x, xt);
    }
    deform_mfma_kernel<<<4 * 64 * 2, 512, 0, stream>>>(x, off, w, wfrag, xt, out, mode);
}